// Round 4
// baseline (319.797 us; speedup 1.0000x reference)
//
#include <hip/hip_runtime.h>

#define TOKENS 16384
#define DDIM 4096
#define RANK 32
#define TOPK 8
#define DSUB 64
#define TILE_T 128
#define NTP 129  // padded token slots: quad=(k4+t)%8 -> conflict-free phases

// ---------------- K1: y_part[db][t][r] = sum_{d in chunk db} x[t][d]*A[r][d]
// grid (TOKENS/128, ndb), block 256 (4 waves). Tile: 128 tokens x 64 dims.
// Each lane owns 2 tokens (lane, lane+64); wave w computes ranks w*8..w*8+7.
// A is wave-uniform (readfirstlane) -> s_load_x16 on the scalar pipe; 2
// tokens/lane doubles the FMA work covering each scalar-load drain.
__global__ __launch_bounds__(256) void k1_proj(const float* __restrict__ x,
                                               const float* __restrict__ A,
                                               float* __restrict__ y_part) {
  const int tid = threadIdx.x;
  const int lane = tid & 63;
  const int wid = __builtin_amdgcn_readfirstlane(tid >> 6);
  const int r0 = wid * 8;
  const int t0 = blockIdx.x * TILE_T;
  const int db = blockIdx.y;
  const int dblk = DDIM / gridDim.y;
  const int nsub = dblk / DSUB;

  // [k4][token(padded 129)][4] float4 slots; write quad=(li+t)%8, read
  // quad=(k4+t)%8 -> exactly 2 lanes per 16B slot per quarter-phase = free.
  __shared__ float xs[16 * NTP * 4];  // 33 KB

  float acc[2][8];
#pragma unroll
  for (int ti = 0; ti < 2; ++ti)
#pragma unroll
    for (int r = 0; r < 8; ++r) acc[ti][r] = 0.f;

  const int li = tid & 15;  // k4 group (dim/4) for staging
  const int th = tid >> 4;  // 0..15 token base

  for (int sub = 0; sub < nsub; ++sub) {
    const int d0 = db * dblk + sub * DSUB;
    // stage 128 tokens x 64 dims: 256 thr x 8 float4, 256B segments/row
#pragma unroll
    for (int jj = 0; jj < 8; ++jj) {
      const int trow = th + jj * 16;
      const float4 v = *reinterpret_cast<const float4*>(
          &x[(size_t)(t0 + trow) * DDIM + d0 + li * 4]);
      *reinterpret_cast<float4*>(&xs[(li * NTP + trow) * 4]) = v;
    }
    __syncthreads();

#pragma unroll
    for (int c = 0; c < 4; ++c) {
      float xv[2][16];
#pragma unroll
      for (int j = 0; j < 4; ++j) {
        const int k4 = c * 4 + j;
#pragma unroll
        for (int ti = 0; ti < 2; ++ti) {
          const float4 v = *reinterpret_cast<const float4*>(
              &xs[(k4 * NTP + lane + ti * 64) * 4]);
          xv[ti][j * 4 + 0] = v.x; xv[ti][j * 4 + 1] = v.y;
          xv[ti][j * 4 + 2] = v.z; xv[ti][j * 4 + 3] = v.w;
        }
      }
#pragma unroll
      for (int r = 0; r < 8; ++r) {
        const float* Ar = &A[(size_t)(r0 + r) * DDIM + d0 + c * 16];
        float sa = 0.f, sb = 0.f;
#pragma unroll
        for (int k = 0; k < 16; ++k) {
          const float av = Ar[k];  // uniform -> SGPR
          sa = fmaf(xv[0][k], av, sa);
          sb = fmaf(xv[1][k], av, sb);
        }
        acc[0][r] += sa;  // two-level fp32 accumulation (tight vs np ref)
        acc[1][r] += sb;
      }
    }
    __syncthreads();
  }

#pragma unroll
  for (int ti = 0; ti < 2; ++ti) {
    float* yp =
        &y_part[((size_t)db * TOKENS + t0 + lane + ti * 64) * RANK + r0];
    float4 o0 = {acc[ti][0], acc[ti][1], acc[ti][2], acc[ti][3]};
    float4 o1 = {acc[ti][4], acc[ti][5], acc[ti][6], acc[ti][7]};
    reinterpret_cast<float4*>(yp)[0] = o0;
    reinterpret_cast<float4*>(yp)[1] = o1;
  }
}

// ---------------- K2: reduce partials, bias, |.| top-8, w = 2*y*mask -------
__global__ __launch_bounds__(64) void k2_topk(const float* __restrict__ y_part,
                                              const float* __restrict__ dbias,
                                              float* __restrict__ w, int ndb) {
  const int t = blockIdx.x * 64 + threadIdx.x;
  float yv[RANK];
#pragma unroll
  for (int r = 0; r < RANK; ++r) yv[r] = 0.f;
  for (int c = 0; c < ndb; ++c) {
    const float* yp = &y_part[((size_t)c * TOKENS + t) * RANK];
#pragma unroll
    for (int q = 0; q < RANK / 4; ++q) {
      const float4 v = reinterpret_cast<const float4*>(yp)[q];
      yv[q * 4 + 0] += v.x; yv[q * 4 + 1] += v.y;
      yv[q * 4 + 2] += v.z; yv[q * 4 + 3] += v.w;
    }
  }

  float ab[RANK];
#pragma unroll
  for (int r = 0; r < RANK; ++r) ab[r] = fabsf(yv[r] + dbias[r]);

  unsigned mask = 0;
#pragma unroll
  for (int k = 0; k < TOPK; ++k) {
    float best = -1.f;
    int bi = 0;
#pragma unroll
    for (int r = 0; r < RANK; ++r) {
      // strict > keeps lowest index on ties == jax.lax.top_k stability
      const bool sel = (((mask >> r) & 1u) == 0u) && (ab[r] > best);
      best = sel ? ab[r] : best;
      bi = sel ? r : bi;
    }
    mask |= 1u << bi;
  }

  float* wp = &w[(size_t)t * RANK];
#pragma unroll
  for (int q = 0; q < RANK / 4; ++q) {
    float4 o;
    o.x = ((mask >> (q * 4 + 0)) & 1u) ? 2.0f * yv[q * 4 + 0] : 0.f;
    o.y = ((mask >> (q * 4 + 1)) & 1u) ? 2.0f * yv[q * 4 + 1] : 0.f;
    o.z = ((mask >> (q * 4 + 2)) & 1u) ? 2.0f * yv[q * 4 + 2] : 0.f;
    o.w = ((mask >> (q * 4 + 3)) & 1u) ? 2.0f * yv[q * 4 + 3] : 0.f;
    reinterpret_cast<float4*>(wp)[q] = o;
  }
}

// ---------------- K3: out[t][o] = sum_r w[t][r] * B[o][r] ----------------
// grid (DDIM/512, TOKENS/64), block 256. w rows staged in LDS; per-token
// reads are uniform-broadcast ds_read_b128 (in-order -> partial lgkmcnt
// waits pipeline across tokens, unlike s_load's lgkmcnt(0) drain).
#define K3_TOK 64

__global__ __launch_bounds__(256) void k3_out(const float* __restrict__ w,
                                              const float* __restrict__ B,
                                              float* __restrict__ out) {
  const int tid = threadIdx.x;
  const int c0 = blockIdx.x * 512 + tid * 2;
  const int tbase = blockIdx.y * K3_TOK;

  __shared__ float wl[K3_TOK * RANK];  // 8 KB

  float b0[RANK], b1[RANK];
#pragma unroll
  for (int q = 0; q < RANK / 4; ++q) {
    const float4 v0 = reinterpret_cast<const float4*>(&B[(size_t)c0 * RANK])[q];
    const float4 v1 =
        reinterpret_cast<const float4*>(&B[(size_t)(c0 + 1) * RANK])[q];
    b0[q * 4 + 0] = v0.x; b0[q * 4 + 1] = v0.y;
    b0[q * 4 + 2] = v0.z; b0[q * 4 + 3] = v0.w;
    b1[q * 4 + 0] = v1.x; b1[q * 4 + 1] = v1.y;
    b1[q * 4 + 2] = v1.z; b1[q * 4 + 3] = v1.w;
  }

  // stage w[tbase..tbase+64)[0..32): 2048 contiguous floats, coalesced
  const float4* wg = reinterpret_cast<const float4*>(&w[(size_t)tbase * RANK]);
#pragma unroll
  for (int jj = 0; jj < 2; ++jj) {
    const int slot = tid + 256 * jj;  // 512 float4 slots
    reinterpret_cast<float4*>(wl)[slot] = wg[slot];
  }
  __syncthreads();

#pragma unroll 4
  for (int tt = 0; tt < K3_TOK; ++tt) {
    float s0 = 0.f, s1 = 0.f;
#pragma unroll
    for (int q = 0; q < RANK / 4; ++q) {
      const float4 wv = reinterpret_cast<const float4*>(wl)[tt * 8 + q];
      s0 = fmaf(wv.x, b0[q * 4 + 0], s0); s1 = fmaf(wv.x, b1[q * 4 + 0], s1);
      s0 = fmaf(wv.y, b0[q * 4 + 1], s0); s1 = fmaf(wv.y, b1[q * 4 + 1], s1);
      s0 = fmaf(wv.z, b0[q * 4 + 2], s0); s1 = fmaf(wv.z, b1[q * 4 + 2], s1);
      s0 = fmaf(wv.w, b0[q * 4 + 3], s0); s1 = fmaf(wv.w, b1[q * 4 + 3], s1);
    }
    float2 o;
    o.x = s0;
    o.y = s1;
    *reinterpret_cast<float2*>(&out[(size_t)(tbase + tt) * DDIM + c0]) = o;
  }
}

extern "C" void kernel_launch(void* const* d_in, const int* in_sizes, int n_in,
                              void* d_out, int out_size, void* d_ws,
                              size_t ws_size, hipStream_t stream) {
  const float* x = (const float*)d_in[0];
  const float* A = (const float*)d_in[1];
  const float* B = (const float*)d_in[2];
  const float* dbias = (const float*)d_in[3];
  float* out = (float*)d_out;

  const size_t plane = (size_t)TOKENS * RANK;  // 512K floats = 2 MB
  int ndb = 8;
  while (ndb > 1 && ws_size < (size_t)(ndb + 1) * plane * sizeof(float))
    ndb >>= 1;

  float* y_part = (float*)d_ws;             // ndb planes
  float* w = y_part + (size_t)ndb * plane;  // 1 plane

  k1_proj<<<dim3(TOKENS / TILE_T, ndb), 256, 0, stream>>>(x, A, y_part);
  k2_topk<<<TOKENS / 64, 64, 0, stream>>>(y_part, dbias, w, ndb);
  k3_out<<<dim3(DDIM / 512, TOKENS / K3_TOK), 256, 0, stream>>>(w, B, out);
}

// Round 5
// 290.725 us; speedup vs baseline: 1.1000x; 1.1000x over previous
//
#include <hip/hip_runtime.h>

#define TOKENS 16384
#define DDIM 4096
#define RANK 32
#define TOPK 8
#define DSUB 32
#define TILE_T 128
#define NTP 129  // padded token slots -> staging writes/reads <=2 lanes/quad

// ---------------- K1: y_part[db][t][r] = sum_{d in chunk db} x[t][d]*A[r][d]
// grid (TOKENS/128, ndb), block 256 (4 waves). Tile: 128 tokens x 32 dims
// (16.5 KB LDS -> 8 blocks/CU with ndb=16). Lane owns tokens (lane, lane+64);
// wave w computes ranks w*8..w*8+7. A is wave-uniform (readfirstlane) ->
// s_load_x16 scalar pipe; 2 tokens/lane = 64 cy FMA cover per s_load, and
// high occupancy interleaves the residual SMEM drains.
__global__ __launch_bounds__(256) void k1_proj(const float* __restrict__ x,
                                               const float* __restrict__ A,
                                               float* __restrict__ y_part,
                                               int dblk, int nsub) {
  const int tid = threadIdx.x;
  const int lane = tid & 63;
  const int wid = __builtin_amdgcn_readfirstlane(tid >> 6);
  const int r0 = wid * 8;
  const int t0 = blockIdx.x * TILE_T;
  const int db = blockIdx.y;

  __shared__ float xs[8 * NTP * 4];  // [k4 0..7][token(129)][4] = 16.5 KB

  float acc[2][8];
#pragma unroll
  for (int ti = 0; ti < 2; ++ti)
#pragma unroll
    for (int r = 0; r < 8; ++r) acc[ti][r] = 0.f;

  const int li = tid & 7;  // k4 group (dim/4) for staging
  const int th = tid >> 3; // 0..31 token base

  for (int sub = 0; sub < nsub; ++sub) {
    const int d0 = db * dblk + sub * DSUB;
    // stage 128 tokens x 32 dims: 256 thr x 4 float4; 128B contiguous per
    // 8-lane group. Write bank-quad = ((li+th)*4)%32 -> <=2 lanes/quad.
#pragma unroll
    for (int jj = 0; jj < 4; ++jj) {
      const int trow = th + jj * 32;
      const float4 v = *reinterpret_cast<const float4*>(
          &x[(size_t)(t0 + trow) * DDIM + d0 + li * 4]);
      *reinterpret_cast<float4*>(&xs[(li * NTP + trow) * 4]) = v;
    }
    __syncthreads();

#pragma unroll
    for (int c = 0; c < 2; ++c) {
      float xv[2][16];
#pragma unroll
      for (int j = 0; j < 4; ++j) {
        const int k4 = c * 4 + j;
#pragma unroll
        for (int ti = 0; ti < 2; ++ti) {
          const float4 v = *reinterpret_cast<const float4*>(
              &xs[(k4 * NTP + lane + ti * 64) * 4]);
          xv[ti][j * 4 + 0] = v.x; xv[ti][j * 4 + 1] = v.y;
          xv[ti][j * 4 + 2] = v.z; xv[ti][j * 4 + 3] = v.w;
        }
      }
      // 1 s_load_dwordx16 per rank per c; 8 ranks -> deep scalar pipeline
#pragma unroll
      for (int r = 0; r < 8; ++r) {
        const float* Ar = &A[(size_t)(r0 + r) * DDIM + d0 + c * 16];
        float sa = 0.f, sb = 0.f;
#pragma unroll
        for (int k = 0; k < 16; ++k) {
          const float av = Ar[k];  // uniform -> SGPR
          sa = fmaf(xv[0][k], av, sa);
          sb = fmaf(xv[1][k], av, sb);
        }
        acc[0][r] += sa;  // two-level fp32 accumulation (tight vs np ref)
        acc[1][r] += sb;
      }
    }
    __syncthreads();
  }

#pragma unroll
  for (int ti = 0; ti < 2; ++ti) {
    float* yp =
        &y_part[((size_t)db * TOKENS + t0 + lane + ti * 64) * RANK + r0];
    float4 o0 = {acc[ti][0], acc[ti][1], acc[ti][2], acc[ti][3]};
    float4 o1 = {acc[ti][4], acc[ti][5], acc[ti][6], acc[ti][7]};
    reinterpret_cast<float4*>(yp)[0] = o0;
    reinterpret_cast<float4*>(yp)[1] = o1;
  }
}

// ---------------- K2: reduce partials, bias, |.| top-8, w = 2*y*mask -------
__global__ __launch_bounds__(64) void k2_topk(const float* __restrict__ y_part,
                                              const float* __restrict__ dbias,
                                              float* __restrict__ w, int ndb) {
  const int t = blockIdx.x * 64 + threadIdx.x;
  float yv[RANK];
#pragma unroll
  for (int r = 0; r < RANK; ++r) yv[r] = 0.f;
  for (int c = 0; c < ndb; ++c) {
    const float* yp = &y_part[((size_t)c * TOKENS + t) * RANK];
#pragma unroll
    for (int q = 0; q < RANK / 4; ++q) {
      const float4 v = reinterpret_cast<const float4*>(yp)[q];
      yv[q * 4 + 0] += v.x; yv[q * 4 + 1] += v.y;
      yv[q * 4 + 2] += v.z; yv[q * 4 + 3] += v.w;
    }
  }

  float ab[RANK];
#pragma unroll
  for (int r = 0; r < RANK; ++r) ab[r] = fabsf(yv[r] + dbias[r]);

  unsigned mask = 0;
#pragma unroll
  for (int k = 0; k < TOPK; ++k) {
    float best = -1.f;
    int bi = 0;
#pragma unroll
    for (int r = 0; r < RANK; ++r) {
      // strict > keeps lowest index on ties == jax.lax.top_k stability
      const bool sel = (((mask >> r) & 1u) == 0u) && (ab[r] > best);
      best = sel ? ab[r] : best;
      bi = sel ? r : bi;
    }
    mask |= 1u << bi;
  }

  float* wp = &w[(size_t)t * RANK];
#pragma unroll
  for (int q = 0; q < RANK / 4; ++q) {
    float4 o;
    o.x = ((mask >> (q * 4 + 0)) & 1u) ? 2.0f * yv[q * 4 + 0] : 0.f;
    o.y = ((mask >> (q * 4 + 1)) & 1u) ? 2.0f * yv[q * 4 + 1] : 0.f;
    o.z = ((mask >> (q * 4 + 2)) & 1u) ? 2.0f * yv[q * 4 + 2] : 0.f;
    o.w = ((mask >> (q * 4 + 3)) & 1u) ? 2.0f * yv[q * 4 + 3] : 0.f;
    reinterpret_cast<float4*>(wp)[q] = o;
  }
}

// ---------------- K3: out[t][o] = sum_r w[t][r] * B[o][r] ----------------
// grid (DDIM/512, TOKENS/64), block 256. w rows staged in LDS; per-token
// reads are uniform-broadcast ds_read_b128 (in-order -> partial lgkmcnt
// waits pipeline across tokens).
#define K3_TOK 64

__global__ __launch_bounds__(256) void k3_out(const float* __restrict__ w,
                                              const float* __restrict__ B,
                                              float* __restrict__ out) {
  const int tid = threadIdx.x;
  const int c0 = blockIdx.x * 512 + tid * 2;
  const int tbase = blockIdx.y * K3_TOK;

  __shared__ float wl[K3_TOK * RANK];  // 8 KB

  float b0[RANK], b1[RANK];
#pragma unroll
  for (int q = 0; q < RANK / 4; ++q) {
    const float4 v0 = reinterpret_cast<const float4*>(&B[(size_t)c0 * RANK])[q];
    const float4 v1 =
        reinterpret_cast<const float4*>(&B[(size_t)(c0 + 1) * RANK])[q];
    b0[q * 4 + 0] = v0.x; b0[q * 4 + 1] = v0.y;
    b0[q * 4 + 2] = v0.z; b0[q * 4 + 3] = v0.w;
    b1[q * 4 + 0] = v1.x; b1[q * 4 + 1] = v1.y;
    b1[q * 4 + 2] = v1.z; b1[q * 4 + 3] = v1.w;
  }

  // stage w[tbase..tbase+64)[0..32): 2048 contiguous floats, coalesced
  const float4* wg = reinterpret_cast<const float4*>(&w[(size_t)tbase * RANK]);
#pragma unroll
  for (int jj = 0; jj < 2; ++jj) {
    const int slot = tid + 256 * jj;  // 512 float4 slots
    reinterpret_cast<float4*>(wl)[slot] = wg[slot];
  }
  __syncthreads();

#pragma unroll 4
  for (int tt = 0; tt < K3_TOK; ++tt) {
    float s0 = 0.f, s1 = 0.f;
#pragma unroll
    for (int q = 0; q < RANK / 4; ++q) {
      const float4 wv = reinterpret_cast<const float4*>(wl)[tt * 8 + q];
      s0 = fmaf(wv.x, b0[q * 4 + 0], s0); s1 = fmaf(wv.x, b1[q * 4 + 0], s1);
      s0 = fmaf(wv.y, b0[q * 4 + 1], s0); s1 = fmaf(wv.y, b1[q * 4 + 1], s1);
      s0 = fmaf(wv.z, b0[q * 4 + 2], s0); s1 = fmaf(wv.z, b1[q * 4 + 2], s1);
      s0 = fmaf(wv.w, b0[q * 4 + 3], s0); s1 = fmaf(wv.w, b1[q * 4 + 3], s1);
    }
    float2 o;
    o.x = s0;
    o.y = s1;
    *reinterpret_cast<float2*>(&out[(size_t)(tbase + tt) * DDIM + c0]) = o;
  }
}

extern "C" void kernel_launch(void* const* d_in, const int* in_sizes, int n_in,
                              void* d_out, int out_size, void* d_ws,
                              size_t ws_size, hipStream_t stream) {
  const float* x = (const float*)d_in[0];
  const float* A = (const float*)d_in[1];
  const float* B = (const float*)d_in[2];
  const float* dbias = (const float*)d_in[3];
  float* out = (float*)d_out;

  const size_t plane = (size_t)TOKENS * RANK;  // 512K floats = 2 MB
  int ndb = 16;  // 2048 k1 blocks = 8/CU co-resident
  while (ndb > 1 && ws_size < (size_t)(ndb + 1) * plane * sizeof(float))
    ndb >>= 1;
  const int dblk = DDIM / ndb;
  const int nsub = dblk / DSUB;

  float* y_part = (float*)d_ws;             // ndb planes
  float* w = y_part + (size_t)ndb * plane;  // 1 plane

  k1_proj<<<dim3(TOKENS / TILE_T, ndb), 256, 0, stream>>>(x, A, y_part, dblk,
                                                          nsub);
  k2_topk<<<TOKENS / 64, 64, 0, stream>>>(y_part, dbias, w, ndb);
  k3_out<<<dim3(DDIM / 512, TOKENS / K3_TOK), 256, 0, stream>>>(w, B, out);
}